// Round 17
// baseline (115.246 us; speedup 1.0000x reference)
//
#include <hip/hip_runtime.h>
#include <hip/hip_bf16.h>
#include <math.h>

#define B_ 2
#define S_ 2048
#define D_ 1024
#define H_ 16
#define DK_ 64

typedef __bf16 bf16_t;
typedef bf16_t bf16x8 __attribute__((ext_vector_type(8)));
typedef bf16_t bf16x4 __attribute__((ext_vector_type(4)));
typedef float f32x4 __attribute__((ext_vector_type(4)));

// async global->LDS, 16B per lane. LDS dest base must be wave-uniform; HW adds lane*16.
__device__ __forceinline__ void gload16(const void* g, void* lds_base_uniform) {
  __builtin_amdgcn_global_load_lds(
      (const __attribute__((address_space(1))) unsigned int*)g,
      (__attribute__((address_space(3))) unsigned int*)lds_base_uniform, 16, 0, 0);
}

// Explicit drain of LDS-DMA (global_load_lds counts in vmcnt, NOT lgkmcnt).
// Required before any barrier that publishes gload16 data (fixed R13's
// post-timing divergence).
__device__ __forceinline__ void drain_ldsdma() {
  asm volatile("s_waitcnt vmcnt(0)" ::: "memory");
}

// ---------------- single cast kernel: x -> xb, W* -> Wcat||Wob (contig) -----
__global__ __launch_bounds__(256) void cast_all(const float* __restrict__ x,
                                                const float* __restrict__ Wq,
                                                const float* __restrict__ Wk,
                                                const float* __restrict__ Wv,
                                                const float* __restrict__ Wo,
                                                bf16_t* __restrict__ out) {
  int i = blockIdx.x * 256 + threadIdx.x;   // 2,097,152 float4 groups total
  int r = i >> 18;                           // 0..3 = x, 4..7 = Wq/Wk/Wv/Wo
  const float* src = (r < 4) ? x : (r == 4) ? Wq : (r == 5) ? Wk : (r == 6) ? Wv : Wo;
  int off = (r < 4) ? i : (i & 262143);
  float4 f = reinterpret_cast<const float4*>(src)[off];
  bf16x4 o;
  o[0] = (bf16_t)f.x; o[1] = (bf16_t)f.y; o[2] = (bf16_t)f.z; o[3] = (bf16_t)f.w;
  reinterpret_cast<bf16x4*>(out)[i] = o;
}

// ---------------- GEMM, 128x128 tile, 8 waves (2Mx4N of 64x32), swizzled LDS,
// double-buffered 2-phase pipeline (attn-proven schedule: stage-next before
// compute-current, drain+barrier at tail).
template <bool OUT_F32>
__global__ __launch_bounds__(512) void gemm_bt(const bf16_t* __restrict__ A,
                                               const bf16_t* __restrict__ W,
                                               void* __restrict__ Cout,
                                               int Ndim, int Kdim) {
  __shared__ __attribute__((aligned(16))) bf16_t As[2][128][64];
  __shared__ __attribute__((aligned(16))) bf16_t Bs[2][128][64];
  const int bm = blockIdx.x * 128;
  const int bn = blockIdx.y * 128;
  const int tid = threadIdx.x;
  const int lane = tid & 63;
  const int w = tid >> 6;
  const int wm = w >> 2, wn = w & 3;
  const int srow_c = lane >> 3;
  const int sslot = lane & 7;

  f32x4 acc[4][2];
  for (int m = 0; m < 4; ++m)
    for (int n = 0; n < 2; ++n) acc[m][n] = (f32x4){0.f, 0.f, 0.f, 0.f};

  // stage K-step k0 into buffer buf (pre-swizzled source slot, rule #21)
  auto stage = [&](int buf, int k0) {
#pragma unroll
    for (int it = 0; it < 2; ++it) {
      const int c = 2 * w + it;
      const int row = c * 8 + srow_c;
      const int col = ((sslot ^ (row & 7)) << 3);
      gload16(&A[(size_t)(bm + row) * Kdim + k0 + col], (char*)&As[buf][0][0] + c * 1024);
      gload16(&W[(size_t)(bn + row) * Kdim + k0 + col], (char*)&Bs[buf][0][0] + c * 1024);
    }
  };

  stage(0, 0);
  drain_ldsdma();
  __syncthreads();

  int cur = 0;
  for (int k0 = 0; k0 < Kdim; k0 += 64) {
    if (k0 + 64 < Kdim) stage(cur ^ 1, k0 + 64);   // overlap with compute below
#pragma unroll
    for (int t = 0; t < 2; ++t) {
      const int slot0 = t * 4 + (lane >> 4);
      bf16x8 af[4], bfr[2];
#pragma unroll
      for (int m = 0; m < 4; ++m) {
        const int R = wm * 64 + m * 16 + (lane & 15);
        af[m] = *reinterpret_cast<const bf16x8*>(
            (const char*)&As[cur][0][0] + R * 128 + ((slot0 ^ (R & 7)) << 4));
      }
#pragma unroll
      for (int n = 0; n < 2; ++n) {
        const int R = wn * 32 + n * 16 + (lane & 15);
        bfr[n] = *reinterpret_cast<const bf16x8*>(
            (const char*)&Bs[cur][0][0] + R * 128 + ((slot0 ^ (R & 7)) << 4));
      }
#pragma unroll
      for (int m = 0; m < 4; ++m)
#pragma unroll
        for (int n = 0; n < 2; ++n)
          acc[m][n] = __builtin_amdgcn_mfma_f32_16x16x32_bf16(af[m], bfr[n], acc[m][n], 0, 0, 0);
    }
    drain_ldsdma();    // next buffer fully landed; current reads done
    __syncthreads();
    cur ^= 1;
  }

  const int rg = (lane >> 4) << 2, c0 = lane & 15;
#pragma unroll
  for (int m = 0; m < 4; ++m)
#pragma unroll
    for (int n = 0; n < 2; ++n) {
      int r = bm + wm * 64 + m * 16 + rg;
      int c = bn + wn * 32 + n * 16 + c0;
#pragma unroll
      for (int i = 0; i < 4; ++i) {
        if (OUT_F32)
          reinterpret_cast<float*>(Cout)[(size_t)(r + i) * Ndim + c] = acc[m][n][i];
        else
          reinterpret_cast<bf16_t*>(Cout)[(size_t)(r + i) * Ndim + c] = (bf16_t)acc[m][n][i];
      }
    }
}

// ---------------- fused QKV GEMM + RoPE + head reorder + V transpose --------
// Q pre-scaled by 0.125*log2(e) so attention can use exp2 directly.
// Same double-buffered 2-phase pipeline; epilogue bounces C-tile via As (32KB).
__global__ __launch_bounds__(512) void gemm_qkv(const bf16_t* __restrict__ A,
                                                const bf16_t* __restrict__ W,
                                                const int* __restrict__ posids,
                                                bf16_t* __restrict__ Qr,
                                                bf16_t* __restrict__ Kr,
                                                bf16_t* __restrict__ Vt) {
  __shared__ __attribute__((aligned(16))) bf16_t As[2][128][64];
  __shared__ __attribute__((aligned(16))) bf16_t Bs[2][128][64];
  const int bm = blockIdx.x * 128;
  const int bn = blockIdx.y * 128;
  const int tid = threadIdx.x;
  const int lane = tid & 63;
  const int w = tid >> 6;
  const int wm = w >> 2, wn = w & 3;
  const int srow_c = lane >> 3;
  const int sslot = lane & 7;
  const int Kdim = 1024;

  f32x4 acc[4][2];
  for (int m = 0; m < 4; ++m)
    for (int n = 0; n < 2; ++n) acc[m][n] = (f32x4){0.f, 0.f, 0.f, 0.f};

  auto stage = [&](int buf, int k0) {
#pragma unroll
    for (int it = 0; it < 2; ++it) {
      const int c = 2 * w + it;
      const int row = c * 8 + srow_c;
      const int col = ((sslot ^ (row & 7)) << 3);
      gload16(&A[(size_t)(bm + row) * Kdim + k0 + col], (char*)&As[buf][0][0] + c * 1024);
      gload16(&W[(size_t)(bn + row) * Kdim + k0 + col], (char*)&Bs[buf][0][0] + c * 1024);
    }
  };

  stage(0, 0);
  drain_ldsdma();
  __syncthreads();

  int cur = 0;
  for (int k0 = 0; k0 < Kdim; k0 += 64) {
    if (k0 + 64 < Kdim) stage(cur ^ 1, k0 + 64);
#pragma unroll
    for (int t = 0; t < 2; ++t) {
      const int slot0 = t * 4 + (lane >> 4);
      bf16x8 af[4], bfr[2];
#pragma unroll
      for (int m = 0; m < 4; ++m) {
        const int R = wm * 64 + m * 16 + (lane & 15);
        af[m] = *reinterpret_cast<const bf16x8*>(
            (const char*)&As[cur][0][0] + R * 128 + ((slot0 ^ (R & 7)) << 4));
      }
#pragma unroll
      for (int n = 0; n < 2; ++n) {
        const int R = wn * 32 + n * 16 + (lane & 15);
        bfr[n] = *reinterpret_cast<const bf16x8*>(
            (const char*)&Bs[cur][0][0] + R * 128 + ((slot0 ^ (R & 7)) << 4));
      }
#pragma unroll
      for (int m = 0; m < 4; ++m)
#pragma unroll
        for (int n = 0; n < 2; ++n)
          acc[m][n] = __builtin_amdgcn_mfma_f32_16x16x32_bf16(af[m], bfr[n], acc[m][n], 0, 0, 0);
    }
    drain_ldsdma();
    __syncthreads();
    cur ^= 1;
  }

  // ---- fused epilogue (bounce via As: 32KB contiguous) ----
  const int region = bn >> 10;            // 0=Q, 1=K, 2=V
  const int h0 = (bn & 1023) >> 6;
  const int b = bm >> 11;
  const int sblk = bm & 2047;
  char* Cs = (char*)&As[0][0][0];
  const int rg = (lane >> 4) << 2, c0 = lane & 15;

  __syncthreads();

  if (region < 2) {
#pragma unroll
    for (int m = 0; m < 4; ++m)
#pragma unroll
      for (int n = 0; n < 2; ++n) {
        const int col = wn * 32 + n * 16 + c0;
#pragma unroll
        for (int i = 0; i < 4; ++i) {
          const int row = wm * 64 + m * 16 + rg + i;
          *(bf16_t*)(Cs + row * 256 + ((col * 2) ^ ((row & 15) << 4))) = (bf16_t)acc[m][n][i];
        }
      }
    __syncthreads();
    const int sl = tid >> 2;
    const int hh = (tid >> 1) & 1;
    const int jh = tid & 1;
    const int s = sblk + sl;
    const int bh = b * 16 + h0 + hh;
    const int p = posids[b * 2048 + s];
    bf16_t* outp = (region == 0 ? Qr : Kr) + ((size_t)bh * 2048 + s) * 64;
    // Q scale folds 1/sqrt(dk) * log2(e) for exp2-based softmax
    const float qscale = region == 0 ? 0.18033688011112042f : 1.0f;
#pragma unroll
    for (int jj = 0; jj < 4; ++jj) {
      const int j = jh * 4 + jj;
      const int slot = hh * 8 + j;
      bf16x8 v = *(const bf16x8*)(Cs + sl * 256 + ((slot ^ (sl & 15)) << 4));
      bf16x8 ov;
#pragma unroll
      for (int e = 0; e < 8; e += 2) {
        const int ii = j * 4 + (e >> 1);
        float sn, cs2;
        __sincosf((float)p * __expf(-(float)(2 * ii) * (9.210340371976184f / 64.0f)),
                  &sn, &cs2);
        const float x1 = (float)v[e], x2 = (float)v[e + 1];
        ov[e]     = (bf16_t)((cs2 * x1 - sn * x2) * qscale);
        ov[e + 1] = (bf16_t)((sn * x1 + cs2 * x2) * qscale);
      }
      *(bf16x8*)(&outp[j * 8]) = ov;
    }
  } else {
#pragma unroll
    for (int m = 0; m < 4; ++m)
#pragma unroll
      for (int n = 0; n < 2; ++n) {
        const int col = wn * 32 + n * 16 + c0;
        const int row0 = wm * 64 + m * 16 + rg;
        bf16x4 pk;
#pragma unroll
        for (int i = 0; i < 4; ++i) pk[i] = (bf16_t)acc[m][n][i];
        *(bf16x4*)(Cs + col * 256 + ((row0 * 2) ^ ((col & 15) << 4))) = pk;
      }
    __syncthreads();
    const int dloc = tid >> 2;
    const int sg2 = (tid >> 1) & 1;
    const int jh = tid & 1;
    const int bh = b * 16 + h0 + (dloc >> 6);
    const int d = dloc & 63;
    bf16_t* outp = Vt + ((size_t)bh * 64 + d) * 2048 + sblk + sg2 * 64;
#pragma unroll
    for (int jj = 0; jj < 4; ++jj) {
      const int j = jh * 4 + jj;
      bf16x8 v = *(const bf16x8*)(Cs + dloc * 256 + (((sg2 * 8 + j) ^ (dloc & 15)) << 4));
      *(bf16x8*)(&outp[j * 8]) = v;
    }
  }
}

// ---------------- causal flash attention (R14/R16 structure, unchanged) ------
// grid: 1024 blocks, 256 threads (4 waves). Block = (bh = linear&31,
// qt = 31 - (linear>>5)). Wave w owns q-rows [qt*64+16w, +16); lane owns
// q = lane&15. Scores arrive pre-scaled to base-2 (Q folded 0.125*log2e).
// Defer-max + per-lane lrow partials: common-path tile has zero shuffles.
__global__ __launch_bounds__(256) void attn_kernel(const bf16_t* __restrict__ Qr,
                                                   const bf16_t* __restrict__ Kr,
                                                   const bf16_t* __restrict__ Vt,
                                                   bf16_t* __restrict__ AO) {
  const int linear = blockIdx.x;
  const int bh = linear & 31;
  const int qt = 31 - (linear >> 5);
  const int b = bh >> 4, h = bh & 15;
  const bf16_t* Qp = Qr + (size_t)bh * S_ * 64;
  const char* Kbase = (const char*)(Kr + (size_t)bh * S_ * 64);
  const char* Vbase = (const char*)(Vt + (size_t)bh * 64 * S_);
  const int tid = threadIdx.x, lane = tid & 63, w = tid >> 6;
  const int qb = qt * 64;
  const int nt = qt + 1;

  __shared__ __attribute__((aligned(16))) bf16_t Ksm[2][64][64];
  __shared__ __attribute__((aligned(16))) bf16_t Vts[2][64][64];
  __shared__ __attribute__((aligned(16))) bf16_t Psm[4][16][64];

  const int srow = lane >> 3;
  const int sslot = lane & 7;

  bf16x8 qf[2];
  {
    int qrow = qb + w * 16 + (lane & 15);
#pragma unroll
    for (int t = 0; t < 2; ++t)
      qf[t] = *reinterpret_cast<const bf16x8*>(
          &Qp[(size_t)qrow * 64 + t * 32 + ((lane >> 4) << 3)]);
  }

  f32x4 o[4];
  for (int m = 0; m < 4; ++m) o[m] = (f32x4){0.f, 0.f, 0.f, 0.f};
  float mrow = -1e30f, lrow = 0.f;   // lrow is a PER-LANE partial

#pragma unroll
  for (int it = 0; it < 2; ++it) {
    int c = 2 * w + it;
    int row = c * 8 + srow;
    gload16(Kbase + (size_t)row * 128 + ((sslot ^ (row & 7)) << 4),
            (char*)&Ksm[0][0][0] + c * 1024);
    gload16(Vbase + (size_t)row * (S_ * 2) + ((sslot ^ (row & 7)) << 4),
            (char*)&Vts[0][0][0] + c * 1024);
  }
  drain_ldsdma();
  __syncthreads();

  int cur = 0;
#pragma unroll 1
  for (int kt = 0; kt < nt; ++kt) {
    if (kt + 1 < nt) {
#pragma unroll
      for (int it = 0; it < 2; ++it) {
        int c = 2 * w + it;
        int row = c * 8 + srow;
        gload16(Kbase + (size_t)(kt + 1) * 8192 + (size_t)row * 128 + ((sslot ^ (row & 7)) << 4),
                (char*)&Ksm[cur ^ 1][0][0] + c * 1024);
        gload16(Vbase + (size_t)row * (S_ * 2) + (size_t)(kt + 1) * 128 + ((sslot ^ (row & 7)) << 4),
                (char*)&Vts[cur ^ 1][0][0] + c * 1024);
      }
    }

    // ---- S^T = K Q^T (scores already in base-2 units) ----
    f32x4 sacc[4];
    for (int m = 0; m < 4; ++m) sacc[m] = (f32x4){0.f, 0.f, 0.f, 0.f};
    __builtin_amdgcn_s_setprio(1);
#pragma unroll
    for (int t = 0; t < 2; ++t) {
      const int slot0 = t * 4 + (lane >> 4);
#pragma unroll
      for (int m = 0; m < 4; ++m) {
        const int R = m * 16 + (lane & 15);
        bf16x8 kfr = *reinterpret_cast<const bf16x8*>(
            (const char*)&Ksm[cur][0][0] + R * 128 + ((slot0 ^ (R & 7)) << 4));
        sacc[m] = __builtin_amdgcn_mfma_f32_16x16x32_bf16(kfr, qf[t], sacc[m], 0, 0, 0);
      }
    }
    __builtin_amdgcn_s_setprio(0);

    // ---- causal mask (diagonal tile only in effect) ----
    const int qrow = qb + w * 16 + (lane & 15);
    const int g4 = (lane >> 4) << 2;
    if (kt * 64 + 63 > qb + w * 16) {
#pragma unroll
      for (int m = 0; m < 4; ++m) {
        const int kc0 = kt * 64 + m * 16 + g4;
#pragma unroll
        for (int r = 0; r < 4; ++r)
          if (kc0 + r > qrow) sacc[m][r] = -1e30f;
      }
    }

    // ---- in-lane max (tree) ----
    float a0 = fmaxf(fmaxf(sacc[0][0], sacc[0][1]), fmaxf(sacc[0][2], sacc[0][3]));
    float a1 = fmaxf(fmaxf(sacc[1][0], sacc[1][1]), fmaxf(sacc[1][2], sacc[1][3]));
    float a2 = fmaxf(fmaxf(sacc[2][0], sacc[2][1]), fmaxf(sacc[2][2], sacc[2][3]));
    float a3 = fmaxf(fmaxf(sacc[3][0], sacc[3][1]), fmaxf(sacc[3][2], sacc[3][3]));
    float mx = fmaxf(fmaxf(a0, a1), fmaxf(a2, a3));

    // ---- defer-max: rescale only when some lane's tile-max grew past THR ----
    if (!__all(mx <= mrow + 4.0f)) {
      mx = fmaxf(mx, __shfl_xor(mx, 16, 64));
      mx = fmaxf(mx, __shfl_xor(mx, 32, 64));
      const float mnew = fmaxf(mrow, mx);
      const float alpha = __builtin_amdgcn_exp2f(mrow - mnew);
      mrow = mnew;
      lrow *= alpha;
#pragma unroll
      for (int m = 0; m < 4; ++m)
#pragma unroll
        for (int r = 0; r < 4; ++r) o[m][r] *= alpha;
    }

    // ---- p = 2^(s - m); per-lane partial sum (no shuffles) ----
    float s = 0.f;
#pragma unroll
    for (int m = 0; m < 4; ++m)
#pragma unroll
      for (int r = 0; r < 4; ++r) {
        float p = __builtin_amdgcn_exp2f(sacc[m][r] - mrow);
        sacc[m][r] = p;
        s += p;
      }
    lrow += s;

    // ---- P -> Psm (swizzled [16][64]) ----
    {
      const int q = lane & 15;
      char* pbase = (char*)&Psm[w][0][0] + q * 128;
      const int xm = (q & 7) << 4;
#pragma unroll
      for (int m = 0; m < 4; ++m) {
        bf16x4 pk;
#pragma unroll
        for (int r = 0; r < 4; ++r) pk[r] = (bf16_t)sacc[m][r];
        *reinterpret_cast<bf16x4*>(pbase + (((m << 5) | ((lane >> 4) << 3)) ^ xm)) = pk;
      }
    }

    // ---- O^T += V^T P^T ----
    __builtin_amdgcn_s_setprio(1);
#pragma unroll
    for (int t = 0; t < 2; ++t) {
      const int slot0 = t * 4 + (lane >> 4);
      bf16x8 pf = *reinterpret_cast<const bf16x8*>(
          (const char*)&Psm[w][0][0] + (lane & 15) * 128 +
          (((t << 6) | ((lane >> 4) << 4)) ^ ((lane & 7) << 4)));
#pragma unroll
      for (int m = 0; m < 4; ++m) {
        const int R = m * 16 + (lane & 15);
        bf16x8 vf = *reinterpret_cast<const bf16x8*>(
            (const char*)&Vts[cur][0][0] + R * 128 + ((slot0 ^ (R & 7)) << 4));
        o[m] = __builtin_amdgcn_mfma_f32_16x16x32_bf16(vf, pf, o[m], 0, 0, 0);
      }
    }
    __builtin_amdgcn_s_setprio(0);

    drain_ldsdma();      // prefetch for kt+1 fully landed before buffer swap
    __syncthreads();
    cur ^= 1;
  }

  // ---- epilogue: reduce lrow partials once, then normalize ----
  {
    lrow += __shfl_xor(lrow, 16, 64);
    lrow += __shfl_xor(lrow, 32, 64);
    const int q = lane & 15;
    const int g4e = (lane >> 4) << 2;
    const int srw = qb + w * 16 + q;
    const float inv = 1.0f / lrow;
#pragma unroll
    for (int m = 0; m < 4; ++m) {
      bf16x4 ov;
#pragma unroll
      for (int r = 0; r < 4; ++r) ov[r] = (bf16_t)(o[m][r] * inv);
      *reinterpret_cast<bf16x4*>(
          &AO[((size_t)(b * S_ + srw)) * 1024 + h * 64 + m * 16 + g4e]) = ov;
    }
  }
}

// ---------------- launch -----------------------------------------------------
extern "C" void kernel_launch(void* const* d_in, const int* in_sizes, int n_in,
                              void* d_out, int out_size, void* d_ws, size_t ws_size,
                              hipStream_t stream) {
  const float* x  = (const float*)d_in[0];
  const float* Wq = (const float*)d_in[1];
  const float* Wk = (const float*)d_in[2];
  const float* Wv = (const float*)d_in[3];
  const float* Wo = (const float*)d_in[4];
  const int* tp   = (const int*)d_in[5];

  char* ws = (char*)d_ws;
  bf16_t* xb   = (bf16_t*)(ws);               // 4096x1024      (8 MB)
  bf16_t* Wcat = (bf16_t*)(ws + 8388608);     // 3072x1024      (6 MB)
  bf16_t* Wob  = (bf16_t*)(ws + 14680064);    // 1024x1024      (2 MB)  [contig after Wcat]
  bf16_t* Qr   = (bf16_t*)(ws + 41943040);    // (B,H,S,64)     (8 MB)
  bf16_t* Kr   = (bf16_t*)(ws + 50331648);    // (8 MB)
  bf16_t* Vt   = (bf16_t*)(ws + 58720256);    // (B,H,64,S)     (8 MB)
  bf16_t* AO   = (bf16_t*)(ws + 67108864);    // 4096x1024      (8 MB)

  cast_all<<<dim3(8192), dim3(256), 0, stream>>>(x, Wq, Wk, Wv, Wo, (bf16_t*)ws);

  gemm_qkv<<<dim3(32, 24), dim3(512), 0, stream>>>(xb, Wcat, tp, Qr, Kr, Vt);
  attn_kernel<<<dim3(1024), dim3(256), 0, stream>>>(Qr, Kr, Vt, AO);
  gemm_bt<true><<<dim3(32, 8), dim3(512), 0, stream>>>(AO, Wob, d_out, 1024, 1024);

  (void)in_sizes; (void)n_in; (void)out_size; (void)ws_size;
}

// Round 18
// 112.441 us; speedup vs baseline: 1.0249x; 1.0249x over previous
//
#include <hip/hip_runtime.h>
#include <hip/hip_bf16.h>
#include <math.h>

#define B_ 2
#define S_ 2048
#define D_ 1024
#define H_ 16
#define DK_ 64

typedef __bf16 bf16_t;
typedef bf16_t bf16x8 __attribute__((ext_vector_type(8)));
typedef bf16_t bf16x4 __attribute__((ext_vector_type(4)));
typedef float f32x4 __attribute__((ext_vector_type(4)));

// async global->LDS, 16B per lane. LDS dest base must be wave-uniform; HW adds lane*16.
__device__ __forceinline__ void gload16(const void* g, void* lds_base_uniform) {
  __builtin_amdgcn_global_load_lds(
      (const __attribute__((address_space(1))) unsigned int*)g,
      (__attribute__((address_space(3))) unsigned int*)lds_base_uniform, 16, 0, 0);
}

// Explicit drain of LDS-DMA (global_load_lds counts in vmcnt, NOT lgkmcnt).
// Required before any barrier that publishes gload16 data (fixed R13's
// post-timing divergence).
__device__ __forceinline__ void drain_ldsdma() {
  asm volatile("s_waitcnt vmcnt(0)" ::: "memory");
}

// ---------------- single cast kernel: x -> xb, W* -> Wcat||Wob (contig) -----
__global__ __launch_bounds__(256) void cast_all(const float* __restrict__ x,
                                                const float* __restrict__ Wq,
                                                const float* __restrict__ Wk,
                                                const float* __restrict__ Wv,
                                                const float* __restrict__ Wo,
                                                bf16_t* __restrict__ out) {
  int i = blockIdx.x * 256 + threadIdx.x;   // 2,097,152 float4 groups total
  int r = i >> 18;                           // 0..3 = x, 4..7 = Wq/Wk/Wv/Wo
  const float* src = (r < 4) ? x : (r == 4) ? Wq : (r == 5) ? Wk : (r == 6) ? Wv : Wo;
  int off = (r < 4) ? i : (i & 262143);
  float4 f = reinterpret_cast<const float4*>(src)[off];
  bf16x4 o;
  o[0] = (bf16_t)f.x; o[1] = (bf16_t)f.y; o[2] = (bf16_t)f.z; o[3] = (bf16_t)f.w;
  reinterpret_cast<bf16x4*>(out)[i] = o;
}

// ---------------- GEMM, 128x128 tile, 8 waves (2Mx4N of 64x32), swizzled LDS.
template <bool OUT_F32>
__global__ __launch_bounds__(512) void gemm_bt(const bf16_t* __restrict__ A,
                                               const bf16_t* __restrict__ W,
                                               void* __restrict__ Cout,
                                               int Ndim, int Kdim) {
  __shared__ __attribute__((aligned(16))) bf16_t As[128][64];
  __shared__ __attribute__((aligned(16))) bf16_t Bs[128][64];
  const int bm = blockIdx.x * 128;
  const int bn = blockIdx.y * 128;
  const int tid = threadIdx.x;
  const int lane = tid & 63;
  const int w = tid >> 6;
  const int wm = w >> 2, wn = w & 3;
  const int srow_c = lane >> 3;
  const int sslot = lane & 7;

  f32x4 acc[4][2];
  for (int m = 0; m < 4; ++m)
    for (int n = 0; n < 2; ++n) acc[m][n] = (f32x4){0.f, 0.f, 0.f, 0.f};

  for (int k0 = 0; k0 < Kdim; k0 += 64) {
    __syncthreads();
#pragma unroll
    for (int it = 0; it < 2; ++it) {
      const int c = 2 * w + it;
      const int row = c * 8 + srow_c;
      const int col = ((sslot ^ (row & 7)) << 3);
      gload16(&A[(size_t)(bm + row) * Kdim + k0 + col], (char*)&As[0][0] + c * 1024);
      gload16(&W[(size_t)(bn + row) * Kdim + k0 + col], (char*)&Bs[0][0] + c * 1024);
    }
    drain_ldsdma();
    __syncthreads();
#pragma unroll
    for (int t = 0; t < 2; ++t) {
      const int slot0 = t * 4 + (lane >> 4);
      bf16x8 af[4], bfr[2];
#pragma unroll
      for (int m = 0; m < 4; ++m) {
        const int R = wm * 64 + m * 16 + (lane & 15);
        af[m] = *reinterpret_cast<const bf16x8*>(
            (const char*)&As[0][0] + R * 128 + ((slot0 ^ (R & 7)) << 4));
      }
#pragma unroll
      for (int n = 0; n < 2; ++n) {
        const int R = wn * 32 + n * 16 + (lane & 15);
        bfr[n] = *reinterpret_cast<const bf16x8*>(
            (const char*)&Bs[0][0] + R * 128 + ((slot0 ^ (R & 7)) << 4));
      }
#pragma unroll
      for (int m = 0; m < 4; ++m)
#pragma unroll
        for (int n = 0; n < 2; ++n)
          acc[m][n] = __builtin_amdgcn_mfma_f32_16x16x32_bf16(af[m], bfr[n], acc[m][n], 0, 0, 0);
    }
  }

  const int rg = (lane >> 4) << 2, c0 = lane & 15;
#pragma unroll
  for (int m = 0; m < 4; ++m)
#pragma unroll
    for (int n = 0; n < 2; ++n) {
      int r = bm + wm * 64 + m * 16 + rg;
      int c = bn + wn * 32 + n * 16 + c0;
#pragma unroll
      for (int i = 0; i < 4; ++i) {
        if (OUT_F32)
          reinterpret_cast<float*>(Cout)[(size_t)(r + i) * Ndim + c] = acc[m][n][i];
        else
          reinterpret_cast<bf16_t*>(Cout)[(size_t)(r + i) * Ndim + c] = (bf16_t)acc[m][n][i];
      }
    }
}

// ---------------- fused QKV GEMM + RoPE + head reorder + V transpose --------
// Q pre-scaled by 0.125*log2(e) so attention can use exp2 directly.
__global__ __launch_bounds__(512) void gemm_qkv(const bf16_t* __restrict__ A,
                                                const bf16_t* __restrict__ W,
                                                const int* __restrict__ posids,
                                                bf16_t* __restrict__ Qr,
                                                bf16_t* __restrict__ Kr,
                                                bf16_t* __restrict__ Vt) {
  __shared__ __attribute__((aligned(16))) bf16_t SMEM[2][128][64];
  const int bm = blockIdx.x * 128;
  const int bn = blockIdx.y * 128;
  const int tid = threadIdx.x;
  const int lane = tid & 63;
  const int w = tid >> 6;
  const int wm = w >> 2, wn = w & 3;
  const int srow_c = lane >> 3;
  const int sslot = lane & 7;
  const int Kdim = 1024;

  f32x4 acc[4][2];
  for (int m = 0; m < 4; ++m)
    for (int n = 0; n < 2; ++n) acc[m][n] = (f32x4){0.f, 0.f, 0.f, 0.f};

  for (int k0 = 0; k0 < Kdim; k0 += 64) {
    __syncthreads();
#pragma unroll
    for (int it = 0; it < 2; ++it) {
      const int c = 2 * w + it;
      const int row = c * 8 + srow_c;
      const int col = ((sslot ^ (row & 7)) << 3);
      gload16(&A[(size_t)(bm + row) * Kdim + k0 + col], (char*)&SMEM[0][0][0] + c * 1024);
      gload16(&W[(size_t)(bn + row) * Kdim + k0 + col], (char*)&SMEM[1][0][0] + c * 1024);
    }
    drain_ldsdma();
    __syncthreads();
#pragma unroll
    for (int t = 0; t < 2; ++t) {
      const int slot0 = t * 4 + (lane >> 4);
      bf16x8 af[4], bfr[2];
#pragma unroll
      for (int m = 0; m < 4; ++m) {
        const int R = wm * 64 + m * 16 + (lane & 15);
        af[m] = *reinterpret_cast<const bf16x8*>(
            (const char*)&SMEM[0][0][0] + R * 128 + ((slot0 ^ (R & 7)) << 4));
      }
#pragma unroll
      for (int n = 0; n < 2; ++n) {
        const int R = wn * 32 + n * 16 + (lane & 15);
        bfr[n] = *reinterpret_cast<const bf16x8*>(
            (const char*)&SMEM[1][0][0] + R * 128 + ((slot0 ^ (R & 7)) << 4));
      }
#pragma unroll
      for (int m = 0; m < 4; ++m)
#pragma unroll
        for (int n = 0; n < 2; ++n)
          acc[m][n] = __builtin_amdgcn_mfma_f32_16x16x32_bf16(af[m], bfr[n], acc[m][n], 0, 0, 0);
    }
  }

  // ---- fused epilogue ----
  const int region = bn >> 10;            // 0=Q, 1=K, 2=V
  const int h0 = (bn & 1023) >> 6;
  const int b = bm >> 11;
  const int sblk = bm & 2047;
  char* Cs = (char*)&SMEM[0][0][0];
  const int rg = (lane >> 4) << 2, c0 = lane & 15;

  __syncthreads();

  if (region < 2) {
#pragma unroll
    for (int m = 0; m < 4; ++m)
#pragma unroll
      for (int n = 0; n < 2; ++n) {
        const int col = wn * 32 + n * 16 + c0;
#pragma unroll
        for (int i = 0; i < 4; ++i) {
          const int row = wm * 64 + m * 16 + rg + i;
          *(bf16_t*)(Cs + row * 256 + ((col * 2) ^ ((row & 15) << 4))) = (bf16_t)acc[m][n][i];
        }
      }
    __syncthreads();
    const int sl = tid >> 2;
    const int hh = (tid >> 1) & 1;
    const int jh = tid & 1;
    const int s = sblk + sl;
    const int bh = b * 16 + h0 + hh;
    const int p = posids[b * 2048 + s];
    bf16_t* outp = (region == 0 ? Qr : Kr) + ((size_t)bh * 2048 + s) * 64;
    // Q scale folds 1/sqrt(dk) * log2(e) for exp2-based softmax
    const float qscale = region == 0 ? 0.18033688011112042f : 1.0f;
#pragma unroll
    for (int jj = 0; jj < 4; ++jj) {
      const int j = jh * 4 + jj;
      const int slot = hh * 8 + j;
      bf16x8 v = *(const bf16x8*)(Cs + sl * 256 + ((slot ^ (sl & 15)) << 4));
      bf16x8 ov;
#pragma unroll
      for (int e = 0; e < 8; e += 2) {
        const int ii = j * 4 + (e >> 1);
        float sn, cs2;
        __sincosf((float)p * __expf(-(float)(2 * ii) * (9.210340371976184f / 64.0f)),
                  &sn, &cs2);
        const float x1 = (float)v[e], x2 = (float)v[e + 1];
        ov[e]     = (bf16_t)((cs2 * x1 - sn * x2) * qscale);
        ov[e + 1] = (bf16_t)((sn * x1 + cs2 * x2) * qscale);
      }
      *(bf16x8*)(&outp[j * 8]) = ov;
    }
  } else {
#pragma unroll
    for (int m = 0; m < 4; ++m)
#pragma unroll
      for (int n = 0; n < 2; ++n) {
        const int col = wn * 32 + n * 16 + c0;
        const int row0 = wm * 64 + m * 16 + rg;
        bf16x4 pk;
#pragma unroll
        for (int i = 0; i < 4; ++i) pk[i] = (bf16_t)acc[m][n][i];
        *(bf16x4*)(Cs + col * 256 + ((row0 * 2) ^ ((col & 15) << 4))) = pk;
      }
    __syncthreads();
    const int dloc = tid >> 2;
    const int sg2 = (tid >> 1) & 1;
    const int jh = tid & 1;
    const int bh = b * 16 + h0 + (dloc >> 6);
    const int d = dloc & 63;
    bf16_t* outp = Vt + ((size_t)bh * 64 + d) * 2048 + sblk + sg2 * 64;
#pragma unroll
    for (int jj = 0; jj < 4; ++jj) {
      const int j = jh * 4 + jj;
      bf16x8 v = *(const bf16x8*)(Cs + dloc * 256 + (((sg2 * 8 + j) ^ (dloc & 15)) << 4));
      *(bf16x8*)(&outp[j * 8]) = v;
    }
  }
}

// ---------------- causal flash attention (R14/R16 structure) -----------------
// grid: 1024 blocks, 256 threads (4 waves). Block = (bh = linear&31,
// qt = 31 - (linear>>5)). Wave w owns q-rows [qt*64+16w, +16); lane owns
// q = lane&15. Scores arrive pre-scaled to base-2 (Q folded 0.125*log2e).
// Defer-max + per-lane lrow partials: common-path tile has zero shuffles.
__global__ __launch_bounds__(256) void attn_kernel(const bf16_t* __restrict__ Qr,
                                                   const bf16_t* __restrict__ Kr,
                                                   const bf16_t* __restrict__ Vt,
                                                   bf16_t* __restrict__ AO) {
  const int linear = blockIdx.x;
  const int bh = linear & 31;
  const int qt = 31 - (linear >> 5);
  const int b = bh >> 4, h = bh & 15;
  const bf16_t* Qp = Qr + (size_t)bh * S_ * 64;
  const char* Kbase = (const char*)(Kr + (size_t)bh * S_ * 64);
  const char* Vbase = (const char*)(Vt + (size_t)bh * 64 * S_);
  const int tid = threadIdx.x, lane = tid & 63, w = tid >> 6;
  const int qb = qt * 64;
  const int nt = qt + 1;

  __shared__ __attribute__((aligned(16))) bf16_t Ksm[2][64][64];
  __shared__ __attribute__((aligned(16))) bf16_t Vts[2][64][64];
  __shared__ __attribute__((aligned(16))) bf16_t Psm[4][16][64];

  const int srow = lane >> 3;
  const int sslot = lane & 7;

  bf16x8 qf[2];
  {
    int qrow = qb + w * 16 + (lane & 15);
#pragma unroll
    for (int t = 0; t < 2; ++t)
      qf[t] = *reinterpret_cast<const bf16x8*>(
          &Qp[(size_t)qrow * 64 + t * 32 + ((lane >> 4) << 3)]);
  }

  f32x4 o[4];
  for (int m = 0; m < 4; ++m) o[m] = (f32x4){0.f, 0.f, 0.f, 0.f};
  float mrow = -1e30f, lrow = 0.f;   // lrow is a PER-LANE partial

#pragma unroll
  for (int it = 0; it < 2; ++it) {
    int c = 2 * w + it;
    int row = c * 8 + srow;
    gload16(Kbase + (size_t)row * 128 + ((sslot ^ (row & 7)) << 4),
            (char*)&Ksm[0][0][0] + c * 1024);
    gload16(Vbase + (size_t)row * (S_ * 2) + ((sslot ^ (row & 7)) << 4),
            (char*)&Vts[0][0][0] + c * 1024);
  }
  drain_ldsdma();
  __syncthreads();

  int cur = 0;
#pragma unroll 1
  for (int kt = 0; kt < nt; ++kt) {
    if (kt + 1 < nt) {
#pragma unroll
      for (int it = 0; it < 2; ++it) {
        int c = 2 * w + it;
        int row = c * 8 + srow;
        gload16(Kbase + (size_t)(kt + 1) * 8192 + (size_t)row * 128 + ((sslot ^ (row & 7)) << 4),
                (char*)&Ksm[cur ^ 1][0][0] + c * 1024);
        gload16(Vbase + (size_t)row * (S_ * 2) + (size_t)(kt + 1) * 128 + ((sslot ^ (row & 7)) << 4),
                (char*)&Vts[cur ^ 1][0][0] + c * 1024);
      }
    }

    // ---- S^T = K Q^T (scores already in base-2 units) ----
    f32x4 sacc[4];
    for (int m = 0; m < 4; ++m) sacc[m] = (f32x4){0.f, 0.f, 0.f, 0.f};
    __builtin_amdgcn_s_setprio(1);
#pragma unroll
    for (int t = 0; t < 2; ++t) {
      const int slot0 = t * 4 + (lane >> 4);
#pragma unroll
      for (int m = 0; m < 4; ++m) {
        const int R = m * 16 + (lane & 15);
        bf16x8 kfr = *reinterpret_cast<const bf16x8*>(
            (const char*)&Ksm[cur][0][0] + R * 128 + ((slot0 ^ (R & 7)) << 4));
        sacc[m] = __builtin_amdgcn_mfma_f32_16x16x32_bf16(kfr, qf[t], sacc[m], 0, 0, 0);
      }
    }
    __builtin_amdgcn_s_setprio(0);

    // ---- causal mask (diagonal tile only in effect) ----
    const int qrow = qb + w * 16 + (lane & 15);
    const int g4 = (lane >> 4) << 2;
    if (kt * 64 + 63 > qb + w * 16) {
#pragma unroll
      for (int m = 0; m < 4; ++m) {
        const int kc0 = kt * 64 + m * 16 + g4;
#pragma unroll
        for (int r = 0; r < 4; ++r)
          if (kc0 + r > qrow) sacc[m][r] = -1e30f;
      }
    }

    // ---- in-lane max (tree) ----
    float a0 = fmaxf(fmaxf(sacc[0][0], sacc[0][1]), fmaxf(sacc[0][2], sacc[0][3]));
    float a1 = fmaxf(fmaxf(sacc[1][0], sacc[1][1]), fmaxf(sacc[1][2], sacc[1][3]));
    float a2 = fmaxf(fmaxf(sacc[2][0], sacc[2][1]), fmaxf(sacc[2][2], sacc[2][3]));
    float a3 = fmaxf(fmaxf(sacc[3][0], sacc[3][1]), fmaxf(sacc[3][2], sacc[3][3]));
    float mx = fmaxf(fmaxf(a0, a1), fmaxf(a2, a3));

    // ---- defer-max: rescale only when some lane's tile-max grew past THR ----
    if (!__all(mx <= mrow + 4.0f)) {
      mx = fmaxf(mx, __shfl_xor(mx, 16, 64));
      mx = fmaxf(mx, __shfl_xor(mx, 32, 64));
      const float mnew = fmaxf(mrow, mx);
      const float alpha = __builtin_amdgcn_exp2f(mrow - mnew);
      mrow = mnew;
      lrow *= alpha;
#pragma unroll
      for (int m = 0; m < 4; ++m)
#pragma unroll
        for (int r = 0; r < 4; ++r) o[m][r] *= alpha;
    }

    // ---- p = 2^(s - m); per-lane partial sum (no shuffles) ----
    float s = 0.f;
#pragma unroll
    for (int m = 0; m < 4; ++m)
#pragma unroll
      for (int r = 0; r < 4; ++r) {
        float p = __builtin_amdgcn_exp2f(sacc[m][r] - mrow);
        sacc[m][r] = p;
        s += p;
      }
    lrow += s;

    // ---- P -> Psm (swizzled [16][64]) ----
    {
      const int q = lane & 15;
      char* pbase = (char*)&Psm[w][0][0] + q * 128;
      const int xm = (q & 7) << 4;
#pragma unroll
      for (int m = 0; m < 4; ++m) {
        bf16x4 pk;
#pragma unroll
        for (int r = 0; r < 4; ++r) pk[r] = (bf16_t)sacc[m][r];
        *reinterpret_cast<bf16x4*>(pbase + (((m << 5) | ((lane >> 4) << 3)) ^ xm)) = pk;
      }
    }

    // ---- O^T += V^T P^T ----
    __builtin_amdgcn_s_setprio(1);
#pragma unroll
    for (int t = 0; t < 2; ++t) {
      const int slot0 = t * 4 + (lane >> 4);
      bf16x8 pf = *reinterpret_cast<const bf16x8*>(
          (const char*)&Psm[w][0][0] + (lane & 15) * 128 +
          (((t << 6) | ((lane >> 4) << 4)) ^ ((lane & 7) << 4)));
#pragma unroll
      for (int m = 0; m < 4; ++m) {
        const int R = m * 16 + (lane & 15);
        bf16x8 vf = *reinterpret_cast<const bf16x8*>(
            (const char*)&Vts[cur][0][0] + R * 128 + ((slot0 ^ (R & 7)) << 4));
        o[m] = __builtin_amdgcn_mfma_f32_16x16x32_bf16(vf, pf, o[m], 0, 0, 0);
      }
    }
    __builtin_amdgcn_s_setprio(0);

    drain_ldsdma();      // prefetch for kt+1 fully landed before buffer swap
    __syncthreads();
    cur ^= 1;
  }

  // ---- epilogue: reduce lrow partials once, then normalize ----
  {
    lrow += __shfl_xor(lrow, 16, 64);
    lrow += __shfl_xor(lrow, 32, 64);
    const int q = lane & 15;
    const int g4e = (lane >> 4) << 2;
    const int srw = qb + w * 16 + q;
    const float inv = 1.0f / lrow;
#pragma unroll
    for (int m = 0; m < 4; ++m) {
      bf16x4 ov;
#pragma unroll
      for (int r = 0; r < 4; ++r) ov[r] = (bf16_t)(o[m][r] * inv);
      *reinterpret_cast<bf16x4*>(
          &AO[((size_t)(b * S_ + srw)) * 1024 + h * 64 + m * 16 + g4e]) = ov;
    }
  }
}

// ---------------- launch -----------------------------------------------------
extern "C" void kernel_launch(void* const* d_in, const int* in_sizes, int n_in,
                              void* d_out, int out_size, void* d_ws, size_t ws_size,
                              hipStream_t stream) {
  const float* x  = (const float*)d_in[0];
  const float* Wq = (const float*)d_in[1];
  const float* Wk = (const float*)d_in[2];
  const float* Wv = (const float*)d_in[3];
  const float* Wo = (const float*)d_in[4];
  const int* tp   = (const int*)d_in[5];

  char* ws = (char*)d_ws;
  bf16_t* xb   = (bf16_t*)(ws);               // 4096x1024      (8 MB)
  bf16_t* Wcat = (bf16_t*)(ws + 8388608);     // 3072x1024      (6 MB)
  bf16_t* Wob  = (bf16_t*)(ws + 14680064);    // 1024x1024      (2 MB)  [contig after Wcat]
  bf16_t* Qr   = (bf16_t*)(ws + 41943040);    // (B,H,S,64)     (8 MB)
  bf16_t* Kr   = (bf16_t*)(ws + 50331648);    // (8 MB)
  bf16_t* Vt   = (bf16_t*)(ws + 58720256);    // (B,H,64,S)     (8 MB)
  bf16_t* AO   = (bf16_t*)(ws + 67108864);    // 4096x1024      (8 MB)

  cast_all<<<dim3(8192), dim3(256), 0, stream>>>(x, Wq, Wk, Wv, Wo, (bf16_t*)ws);

  gemm_qkv<<<dim3(32, 24), dim3(512), 0, stream>>>(xb, Wcat, tp, Qr, Kr, Vt);
  attn_kernel<<<dim3(1024), dim3(256), 0, stream>>>(Qr, Kr, Vt, AO);
  gemm_bt<true><<<dim3(32, 8), dim3(512), 0, stream>>>(AO, Wob, d_out, 1024, 1024);

  (void)in_sizes; (void)n_in; (void)out_size; (void)ws_size;
}

// Round 19
// 108.634 us; speedup vs baseline: 1.0609x; 1.0350x over previous
//
#include <hip/hip_runtime.h>
#include <hip/hip_bf16.h>
#include <math.h>

#define B_ 2
#define S_ 2048
#define D_ 1024
#define H_ 16
#define DK_ 64

typedef __bf16 bf16_t;
typedef bf16_t bf16x8 __attribute__((ext_vector_type(8)));
typedef bf16_t bf16x4 __attribute__((ext_vector_type(4)));
typedef float f32x4 __attribute__((ext_vector_type(4)));

// async global->LDS, 16B per lane. LDS dest base must be wave-uniform; HW adds lane*16.
__device__ __forceinline__ void gload16(const void* g, void* lds_base_uniform) {
  __builtin_amdgcn_global_load_lds(
      (const __attribute__((address_space(1))) unsigned int*)g,
      (__attribute__((address_space(3))) unsigned int*)lds_base_uniform, 16, 0, 0);
}

// Explicit drain of LDS-DMA (global_load_lds counts in vmcnt, NOT lgkmcnt).
// Required before any barrier that publishes gload16 data (fixed R13's
// post-timing divergence).
__device__ __forceinline__ void drain_ldsdma() {
  asm volatile("s_waitcnt vmcnt(0)" ::: "memory");
}

// ---------------- single cast kernel: x -> xb, W* -> Wcat||Wob (contig) -----
__global__ __launch_bounds__(256) void cast_all(const float* __restrict__ x,
                                                const float* __restrict__ Wq,
                                                const float* __restrict__ Wk,
                                                const float* __restrict__ Wv,
                                                const float* __restrict__ Wo,
                                                bf16_t* __restrict__ out) {
  int i = blockIdx.x * 256 + threadIdx.x;   // 2,097,152 float4 groups total
  int r = i >> 18;                           // 0..3 = x, 4..7 = Wq/Wk/Wv/Wo
  const float* src = (r < 4) ? x : (r == 4) ? Wq : (r == 5) ? Wk : (r == 6) ? Wv : Wo;
  int off = (r < 4) ? i : (i & 262143);
  float4 f = reinterpret_cast<const float4*>(src)[off];
  bf16x4 o;
  o[0] = (bf16_t)f.x; o[1] = (bf16_t)f.y; o[2] = (bf16_t)f.z; o[3] = (bf16_t)f.w;
  reinterpret_cast<bf16x4*>(out)[i] = o;
}

// ---------------- AO GEMM: 128x64 tile, 8 waves (4Mx2N of 32x32), swizzled ---
// C[M,N] = A[M,K] * W[N,K]^T, fp32 out. Grid (M/128, N/64) = (32,16) = 512
// blocks -> all co-resident at 4 blocks/CU (24KB LDS), 16 waves/CU.
__global__ __launch_bounds__(512) void gemm_bt64(const bf16_t* __restrict__ A,
                                                 const bf16_t* __restrict__ W,
                                                 float* __restrict__ Cout,
                                                 int Ndim, int Kdim) {
  __shared__ __attribute__((aligned(16))) bf16_t As[128][64];
  __shared__ __attribute__((aligned(16))) bf16_t Bs[64][64];
  const int bm = blockIdx.x * 128;
  const int bn = blockIdx.y * 64;
  const int tid = threadIdx.x;
  const int lane = tid & 63;
  const int w = tid >> 6;
  const int wm = w >> 1, wn = w & 1;      // 4Mx2N waves, 32x32 each
  const int srow_c = lane >> 3;
  const int sslot = lane & 7;

  f32x4 acc[2][2];
  for (int m = 0; m < 2; ++m)
    for (int n = 0; n < 2; ++n) acc[m][n] = (f32x4){0.f, 0.f, 0.f, 0.f};

  for (int k0 = 0; k0 < Kdim; k0 += 64) {
    __syncthreads();
    {
      // A tile: 16 chunks of 1KB; wave w stages chunks 2w, 2w+1
#pragma unroll
      for (int it = 0; it < 2; ++it) {
        const int c = 2 * w + it;
        const int row = c * 8 + srow_c;
        const int col = ((sslot ^ (row & 7)) << 3);
        gload16(&A[(size_t)(bm + row) * Kdim + k0 + col], (char*)&As[0][0] + c * 1024);
      }
      // B tile: 8 chunks; wave w stages chunk w
      const int rowb = w * 8 + srow_c;
      const int colb = ((sslot ^ (rowb & 7)) << 3);
      gload16(&W[(size_t)(bn + rowb) * Kdim + k0 + colb], (char*)&Bs[0][0] + w * 1024);
    }
    drain_ldsdma();
    __syncthreads();
#pragma unroll
    for (int t = 0; t < 2; ++t) {
      const int slot0 = t * 4 + (lane >> 4);
      bf16x8 af[2], bfr[2];
#pragma unroll
      for (int m = 0; m < 2; ++m) {
        const int R = wm * 32 + m * 16 + (lane & 15);
        af[m] = *reinterpret_cast<const bf16x8*>(
            (const char*)&As[0][0] + R * 128 + ((slot0 ^ (R & 7)) << 4));
      }
#pragma unroll
      for (int n = 0; n < 2; ++n) {
        const int R = wn * 32 + n * 16 + (lane & 15);
        bfr[n] = *reinterpret_cast<const bf16x8*>(
            (const char*)&Bs[0][0] + R * 128 + ((slot0 ^ (R & 7)) << 4));
      }
#pragma unroll
      for (int m = 0; m < 2; ++m)
#pragma unroll
        for (int n = 0; n < 2; ++n)
          acc[m][n] = __builtin_amdgcn_mfma_f32_16x16x32_bf16(af[m], bfr[n], acc[m][n], 0, 0, 0);
    }
  }

  const int rg = (lane >> 4) << 2, c0 = lane & 15;
#pragma unroll
  for (int m = 0; m < 2; ++m)
#pragma unroll
    for (int n = 0; n < 2; ++n) {
      int r = bm + wm * 32 + m * 16 + rg;
      int c = bn + wn * 32 + n * 16 + c0;
#pragma unroll
      for (int i = 0; i < 2 * 2; ++i) {
        if (i < 4)
          Cout[(size_t)(r + i) * Ndim + c] = acc[m][n][i];
      }
    }
}

// ---------------- fused QKV GEMM + RoPE + head reorder + V transpose --------
// Q pre-scaled by 0.125*log2(e) so attention can use exp2 directly.
__global__ __launch_bounds__(512) void gemm_qkv(const bf16_t* __restrict__ A,
                                                const bf16_t* __restrict__ W,
                                                const int* __restrict__ posids,
                                                bf16_t* __restrict__ Qr,
                                                bf16_t* __restrict__ Kr,
                                                bf16_t* __restrict__ Vt) {
  __shared__ __attribute__((aligned(16))) bf16_t SMEM[2][128][64];
  const int bm = blockIdx.x * 128;
  const int bn = blockIdx.y * 128;
  const int tid = threadIdx.x;
  const int lane = tid & 63;
  const int w = tid >> 6;
  const int wm = w >> 2, wn = w & 3;
  const int srow_c = lane >> 3;
  const int sslot = lane & 7;
  const int Kdim = 1024;

  f32x4 acc[4][2];
  for (int m = 0; m < 4; ++m)
    for (int n = 0; n < 2; ++n) acc[m][n] = (f32x4){0.f, 0.f, 0.f, 0.f};

  for (int k0 = 0; k0 < Kdim; k0 += 64) {
    __syncthreads();
#pragma unroll
    for (int it = 0; it < 2; ++it) {
      const int c = 2 * w + it;
      const int row = c * 8 + srow_c;
      const int col = ((sslot ^ (row & 7)) << 3);
      gload16(&A[(size_t)(bm + row) * Kdim + k0 + col], (char*)&SMEM[0][0][0] + c * 1024);
      gload16(&W[(size_t)(bn + row) * Kdim + k0 + col], (char*)&SMEM[1][0][0] + c * 1024);
    }
    drain_ldsdma();
    __syncthreads();
#pragma unroll
    for (int t = 0; t < 2; ++t) {
      const int slot0 = t * 4 + (lane >> 4);
      bf16x8 af[4], bfr[2];
#pragma unroll
      for (int m = 0; m < 4; ++m) {
        const int R = wm * 64 + m * 16 + (lane & 15);
        af[m] = *reinterpret_cast<const bf16x8*>(
            (const char*)&SMEM[0][0][0] + R * 128 + ((slot0 ^ (R & 7)) << 4));
      }
#pragma unroll
      for (int n = 0; n < 2; ++n) {
        const int R = wn * 32 + n * 16 + (lane & 15);
        bfr[n] = *reinterpret_cast<const bf16x8*>(
            (const char*)&SMEM[1][0][0] + R * 128 + ((slot0 ^ (R & 7)) << 4));
      }
#pragma unroll
      for (int m = 0; m < 4; ++m)
#pragma unroll
        for (int n = 0; n < 2; ++n)
          acc[m][n] = __builtin_amdgcn_mfma_f32_16x16x32_bf16(af[m], bfr[n], acc[m][n], 0, 0, 0);
    }
  }

  // ---- fused epilogue ----
  const int region = bn >> 10;            // 0=Q, 1=K, 2=V
  const int h0 = (bn & 1023) >> 6;
  const int b = bm >> 11;
  const int sblk = bm & 2047;
  char* Cs = (char*)&SMEM[0][0][0];
  const int rg = (lane >> 4) << 2, c0 = lane & 15;

  __syncthreads();

  if (region < 2) {
#pragma unroll
    for (int m = 0; m < 4; ++m)
#pragma unroll
      for (int n = 0; n < 2; ++n) {
        const int col = wn * 32 + n * 16 + c0;
#pragma unroll
        for (int i = 0; i < 4; ++i) {
          const int row = wm * 64 + m * 16 + rg + i;
          *(bf16_t*)(Cs + row * 256 + ((col * 2) ^ ((row & 15) << 4))) = (bf16_t)acc[m][n][i];
        }
      }
    __syncthreads();
    const int sl = tid >> 2;
    const int hh = (tid >> 1) & 1;
    const int jh = tid & 1;
    const int s = sblk + sl;
    const int bh = b * 16 + h0 + hh;
    const int p = posids[b * 2048 + s];
    bf16_t* outp = (region == 0 ? Qr : Kr) + ((size_t)bh * 2048 + s) * 64;
    // Q scale folds 1/sqrt(dk) * log2(e) for exp2-based softmax
    const float qscale = region == 0 ? 0.18033688011112042f : 1.0f;
#pragma unroll
    for (int jj = 0; jj < 4; ++jj) {
      const int j = jh * 4 + jj;
      const int slot = hh * 8 + j;
      bf16x8 v = *(const bf16x8*)(Cs + sl * 256 + ((slot ^ (sl & 15)) << 4));
      bf16x8 ov;
#pragma unroll
      for (int e = 0; e < 8; e += 2) {
        const int ii = j * 4 + (e >> 1);
        float sn, cs2;
        __sincosf((float)p * __expf(-(float)(2 * ii) * (9.210340371976184f / 64.0f)),
                  &sn, &cs2);
        const float x1 = (float)v[e], x2 = (float)v[e + 1];
        ov[e]     = (bf16_t)((cs2 * x1 - sn * x2) * qscale);
        ov[e + 1] = (bf16_t)((sn * x1 + cs2 * x2) * qscale);
      }
      *(bf16x8*)(&outp[j * 8]) = ov;
    }
  } else {
#pragma unroll
    for (int m = 0; m < 4; ++m)
#pragma unroll
      for (int n = 0; n < 2; ++n) {
        const int col = wn * 32 + n * 16 + c0;
        const int row0 = wm * 64 + m * 16 + rg;
        bf16x4 pk;
#pragma unroll
        for (int i = 0; i < 4; ++i) pk[i] = (bf16_t)acc[m][n][i];
        *(bf16x4*)(Cs + col * 256 + ((row0 * 2) ^ ((col & 15) << 4))) = pk;
      }
    __syncthreads();
    const int dloc = tid >> 2;
    const int sg2 = (tid >> 1) & 1;
    const int jh = tid & 1;
    const int bh = b * 16 + h0 + (dloc >> 6);
    const int d = dloc & 63;
    bf16_t* outp = Vt + ((size_t)bh * 64 + d) * 2048 + sblk + sg2 * 64;
#pragma unroll
    for (int jj = 0; jj < 4; ++jj) {
      const int j = jh * 4 + jj;
      bf16x8 v = *(const bf16x8*)(Cs + dloc * 256 + (((sg2 * 8 + j) ^ (dloc & 15)) << 4));
      *(bf16x8*)(&outp[j * 8]) = v;
    }
  }
}

// ---------------- causal flash attention (R14/R16 structure) -----------------
// grid: 1024 blocks, 256 threads (4 waves). Block = (bh = linear&31,
// qt = 31 - (linear>>5)). Wave w owns q-rows [qt*64+16w, +16); lane owns
// q = lane&15. Scores arrive pre-scaled to base-2 (Q folded 0.125*log2e).
// Defer-max + per-lane lrow partials: common-path tile has zero shuffles.
__global__ __launch_bounds__(256) void attn_kernel(const bf16_t* __restrict__ Qr,
                                                   const bf16_t* __restrict__ Kr,
                                                   const bf16_t* __restrict__ Vt,
                                                   bf16_t* __restrict__ AO) {
  const int linear = blockIdx.x;
  const int bh = linear & 31;
  const int qt = 31 - (linear >> 5);
  const int b = bh >> 4, h = bh & 15;
  const bf16_t* Qp = Qr + (size_t)bh * S_ * 64;
  const char* Kbase = (const char*)(Kr + (size_t)bh * S_ * 64);
  const char* Vbase = (const char*)(Vt + (size_t)bh * 64 * S_);
  const int tid = threadIdx.x, lane = tid & 63, w = tid >> 6;
  const int qb = qt * 64;
  const int nt = qt + 1;

  __shared__ __attribute__((aligned(16))) bf16_t Ksm[2][64][64];
  __shared__ __attribute__((aligned(16))) bf16_t Vts[2][64][64];
  __shared__ __attribute__((aligned(16))) bf16_t Psm[4][16][64];

  const int srow = lane >> 3;
  const int sslot = lane & 7;

  bf16x8 qf[2];
  {
    int qrow = qb + w * 16 + (lane & 15);
#pragma unroll
    for (int t = 0; t < 2; ++t)
      qf[t] = *reinterpret_cast<const bf16x8*>(
          &Qp[(size_t)qrow * 64 + t * 32 + ((lane >> 4) << 3)]);
  }

  f32x4 o[4];
  for (int m = 0; m < 4; ++m) o[m] = (f32x4){0.f, 0.f, 0.f, 0.f};
  float mrow = -1e30f, lrow = 0.f;   // lrow is a PER-LANE partial

#pragma unroll
  for (int it = 0; it < 2; ++it) {
    int c = 2 * w + it;
    int row = c * 8 + srow;
    gload16(Kbase + (size_t)row * 128 + ((sslot ^ (row & 7)) << 4),
            (char*)&Ksm[0][0][0] + c * 1024);
    gload16(Vbase + (size_t)row * (S_ * 2) + ((sslot ^ (row & 7)) << 4),
            (char*)&Vts[0][0][0] + c * 1024);
  }
  drain_ldsdma();
  __syncthreads();

  int cur = 0;
#pragma unroll 1
  for (int kt = 0; kt < nt; ++kt) {
    if (kt + 1 < nt) {
#pragma unroll
      for (int it = 0; it < 2; ++it) {
        int c = 2 * w + it;
        int row = c * 8 + srow;
        gload16(Kbase + (size_t)(kt + 1) * 8192 + (size_t)row * 128 + ((sslot ^ (row & 7)) << 4),
                (char*)&Ksm[cur ^ 1][0][0] + c * 1024);
        gload16(Vbase + (size_t)row * (S_ * 2) + (size_t)(kt + 1) * 128 + ((sslot ^ (row & 7)) << 4),
                (char*)&Vts[cur ^ 1][0][0] + c * 1024);
      }
    }

    // ---- S^T = K Q^T (scores already in base-2 units) ----
    f32x4 sacc[4];
    for (int m = 0; m < 4; ++m) sacc[m] = (f32x4){0.f, 0.f, 0.f, 0.f};
    __builtin_amdgcn_s_setprio(1);
#pragma unroll
    for (int t = 0; t < 2; ++t) {
      const int slot0 = t * 4 + (lane >> 4);
#pragma unroll
      for (int m = 0; m < 4; ++m) {
        const int R = m * 16 + (lane & 15);
        bf16x8 kfr = *reinterpret_cast<const bf16x8*>(
            (const char*)&Ksm[cur][0][0] + R * 128 + ((slot0 ^ (R & 7)) << 4));
        sacc[m] = __builtin_amdgcn_mfma_f32_16x16x32_bf16(kfr, qf[t], sacc[m], 0, 0, 0);
      }
    }
    __builtin_amdgcn_s_setprio(0);

    // ---- causal mask (diagonal tile only in effect) ----
    const int qrow = qb + w * 16 + (lane & 15);
    const int g4 = (lane >> 4) << 2;
    if (kt * 64 + 63 > qb + w * 16) {
#pragma unroll
      for (int m = 0; m < 4; ++m) {
        const int kc0 = kt * 64 + m * 16 + g4;
#pragma unroll
        for (int r = 0; r < 4; ++r)
          if (kc0 + r > qrow) sacc[m][r] = -1e30f;
      }
    }

    // ---- in-lane max (tree) ----
    float a0 = fmaxf(fmaxf(sacc[0][0], sacc[0][1]), fmaxf(sacc[0][2], sacc[0][3]));
    float a1 = fmaxf(fmaxf(sacc[1][0], sacc[1][1]), fmaxf(sacc[1][2], sacc[1][3]));
    float a2 = fmaxf(fmaxf(sacc[2][0], sacc[2][1]), fmaxf(sacc[2][2], sacc[2][3]));
    float a3 = fmaxf(fmaxf(sacc[3][0], sacc[3][1]), fmaxf(sacc[3][2], sacc[3][3]));
    float mx = fmaxf(fmaxf(a0, a1), fmaxf(a2, a3));

    // ---- defer-max: rescale only when some lane's tile-max grew past THR ----
    if (!__all(mx <= mrow + 4.0f)) {
      mx = fmaxf(mx, __shfl_xor(mx, 16, 64));
      mx = fmaxf(mx, __shfl_xor(mx, 32, 64));
      const float mnew = fmaxf(mrow, mx);
      const float alpha = __builtin_amdgcn_exp2f(mrow - mnew);
      mrow = mnew;
      lrow *= alpha;
#pragma unroll
      for (int m = 0; m < 4; ++m)
#pragma unroll
        for (int r = 0; r < 4; ++r) o[m][r] *= alpha;
    }

    // ---- p = 2^(s - m); per-lane partial sum (no shuffles) ----
    float s = 0.f;
#pragma unroll
    for (int m = 0; m < 4; ++m)
#pragma unroll
      for (int r = 0; r < 4; ++r) {
        float p = __builtin_amdgcn_exp2f(sacc[m][r] - mrow);
        sacc[m][r] = p;
        s += p;
      }
    lrow += s;

    // ---- P -> Psm (swizzled [16][64]) ----
    {
      const int q = lane & 15;
      char* pbase = (char*)&Psm[w][0][0] + q * 128;
      const int xm = (q & 7) << 4;
#pragma unroll
      for (int m = 0; m < 4; ++m) {
        bf16x4 pk;
#pragma unroll
        for (int r = 0; r < 4; ++r) pk[r] = (bf16_t)sacc[m][r];
        *reinterpret_cast<bf16x4*>(pbase + (((m << 5) | ((lane >> 4) << 3)) ^ xm)) = pk;
      }
    }

    // ---- O^T += V^T P^T ----
    __builtin_amdgcn_s_setprio(1);
#pragma unroll
    for (int t = 0; t < 2; ++t) {
      const int slot0 = t * 4 + (lane >> 4);
      bf16x8 pf = *reinterpret_cast<const bf16x8*>(
          (const char*)&Psm[w][0][0] + (lane & 15) * 128 +
          (((t << 6) | ((lane >> 4) << 4)) ^ ((lane & 7) << 4)));
#pragma unroll
      for (int m = 0; m < 4; ++m) {
        const int R = m * 16 + (lane & 15);
        bf16x8 vf = *reinterpret_cast<const bf16x8*>(
            (const char*)&Vts[cur][0][0] + R * 128 + ((slot0 ^ (R & 7)) << 4));
        o[m] = __builtin_amdgcn_mfma_f32_16x16x32_bf16(vf, pf, o[m], 0, 0, 0);
      }
    }
    __builtin_amdgcn_s_setprio(0);

    drain_ldsdma();      // prefetch for kt+1 fully landed before buffer swap
    __syncthreads();
    cur ^= 1;
  }

  // ---- epilogue: reduce lrow partials once, then normalize ----
  {
    lrow += __shfl_xor(lrow, 16, 64);
    lrow += __shfl_xor(lrow, 32, 64);
    const int q = lane & 15;
    const int g4e = (lane >> 4) << 2;
    const int srw = qb + w * 16 + q;
    const float inv = 1.0f / lrow;
#pragma unroll
    for (int m = 0; m < 4; ++m) {
      bf16x4 ov;
#pragma unroll
      for (int r = 0; r < 4; ++r) ov[r] = (bf16_t)(o[m][r] * inv);
      *reinterpret_cast<bf16x4*>(
          &AO[((size_t)(b * S_ + srw)) * 1024 + h * 64 + m * 16 + g4e]) = ov;
    }
  }
}

// ---------------- launch -----------------------------------------------------
extern "C" void kernel_launch(void* const* d_in, const int* in_sizes, int n_in,
                              void* d_out, int out_size, void* d_ws, size_t ws_size,
                              hipStream_t stream) {
  const float* x  = (const float*)d_in[0];
  const float* Wq = (const float*)d_in[1];
  const float* Wk = (const float*)d_in[2];
  const float* Wv = (const float*)d_in[3];
  const float* Wo = (const float*)d_in[4];
  const int* tp   = (const int*)d_in[5];

  char* ws = (char*)d_ws;
  bf16_t* xb   = (bf16_t*)(ws);               // 4096x1024      (8 MB)
  bf16_t* Wcat = (bf16_t*)(ws + 8388608);     // 3072x1024      (6 MB)
  bf16_t* Wob  = (bf16_t*)(ws + 14680064);    // 1024x1024      (2 MB)  [contig after Wcat]
  bf16_t* Qr   = (bf16_t*)(ws + 41943040);    // (B,H,S,64)     (8 MB)
  bf16_t* Kr   = (bf16_t*)(ws + 50331648);    // (8 MB)
  bf16_t* Vt   = (bf16_t*)(ws + 58720256);    // (B,H,64,S)     (8 MB)
  bf16_t* AO   = (bf16_t*)(ws + 67108864);    // 4096x1024      (8 MB)

  cast_all<<<dim3(8192), dim3(256), 0, stream>>>(x, Wq, Wk, Wv, Wo, (bf16_t*)ws);

  gemm_qkv<<<dim3(32, 24), dim3(512), 0, stream>>>(xb, Wcat, tp, Qr, Kr, Vt);
  attn_kernel<<<dim3(1024), dim3(256), 0, stream>>>(Qr, Kr, Vt, AO);
  gemm_bt64<<<dim3(32, 16), dim3(512), 0, stream>>>(AO, Wob, (float*)d_out, 1024, 1024);

  (void)in_sizes; (void)n_in; (void)out_size; (void)ws_size;
}